// Round 7
// baseline (1483.534 us; speedup 1.0000x reference)
//
#include <hip/hip_runtime.h>

// out = mean_i( rank_of_diag(cos_sim(x1,x2))_i < nper ), nper = S/100+1.
// rank_i = #{ j != i : dot(x1_i,x2_j)*inv||x2_j|| > dot(x1_i,x2_i)*inv||x2_i|| }
// GEMM via fp16x3 (Markidis split) MFMA: x=hi+lo; hi*hi + hi*lo + lo*hi.
// Dropped lo*lo ~2^-22 rel/term -> dot err ~3e-6 << 4.5e-3 order-stat spacing.
//
// R7: base = R4 (zero-LDS zero-barrier streamed count, best: 69us) with
//  (1) __launch_bounds__(256,8): request 8 blocks/CU (VGPR 60 fits 64-cap).
//      A/B test: latency-bound -> big win; L3-BW-bound (1GB/69us=14.5TB/s)
//      -> flat, pivot to traffic reduction next.
//  (2) finalize merged into count via device-scope done-counter + last-block
//      reduction (saves a launch + the 1-block kernel).
//  (3) prep rewritten 32-rows/block with LDS-staged fragment assembly ->
//      fully-coalesced uint4 plane writes (was scattered 16B clusters).
//
// Fragment-major plane layout (per plane, halves):
//   addr(row,k) = (row>>5)*4096 + ((k>>5)*2 + ((k>>4)&1))*512
//               + ((k>>3)&1)*256 + (row&31)*8 + (k&7)
// -> 32-row x 16-half fragment = contiguous 1KB, lane reads 16B at +lane*8.

#define KDIM 128

typedef _Float16 half8 __attribute__((ext_vector_type(8)));
typedef float floatx16 __attribute__((ext_vector_type(16)));

// ---------- Kernel A: norms/threshold + coalesced fragment-major fp16 planes ----------
// 256 thr / 32 rows per block; thread (fr=tid>>3, kg=tid&7) owns 16 floats of
// row fr. hi/lo conversion staged in LDS in fragment order, then written out
// as contiguous uint4 streams (fully coalesced).
__global__ __launch_bounds__(256) void prep_kernel(
    const float* __restrict__ x1, const float* __restrict__ x2,
    float* __restrict__ invn, float* __restrict__ thr,
    int* __restrict__ row_count, unsigned* __restrict__ done,
    unsigned* __restrict__ x1h, unsigned* __restrict__ x1l,
    unsigned* __restrict__ x2h, unsigned* __restrict__ x2l,
    int B, int S, int wplanes)
{
    __shared__ __align__(16) unsigned s1h[2048], s1l[2048], s2h[2048], s2l[2048];
    const int tid  = threadIdx.x;
    const int row0 = blockIdx.x * 32;
    const int fr   = tid >> 3;          // row within superblock (0..31)
    const int kg   = tid & 7;           // k16-group (0..7)
    const int r    = row0 + fr;

    if (blockIdx.x == 0 && tid == 0) *done = 0u;

    const bool inB = (r < B);
    const bool inS = (r < S);

    float a[16], b[16];
    float s22 = 0.f, s12 = 0.f;
    if (inB) {
        const float4* p = (const float4*)&x1[(size_t)r * KDIM + kg * 16];
        *(float4*)&a[0]  = p[0];
        *(float4*)&a[4]  = p[1];
        *(float4*)&a[8]  = p[2];
        *(float4*)&a[12] = p[3];
    } else {
        #pragma unroll
        for (int i = 0; i < 16; i++) a[i] = 0.f;
    }
    if (inS) {
        const float4* p = (const float4*)&x2[(size_t)r * KDIM + kg * 16];
        *(float4*)&b[0]  = p[0];
        *(float4*)&b[4]  = p[1];
        *(float4*)&b[8]  = p[2];
        *(float4*)&b[12] = p[3];
        #pragma unroll
        for (int i = 0; i < 16; i++) {
            s22 = fmaf(b[i], b[i], s22);
            s12 = fmaf(a[i], b[i], s12);
        }
    } else {
        #pragma unroll
        for (int i = 0; i < 16; i++) b[i] = 0.f;
    }
    // reduce across the 8 threads of this row (contiguous lanes)
    #pragma unroll
    for (int m = 1; m <= 4; m <<= 1) {
        s22 += __shfl_xor(s22, m);
        s12 += __shfl_xor(s12, m);
    }
    if (kg == 0 && inS) {
        const float iv = rsqrtf(s22);
        invn[r] = iv;
        if (inB) thr[r] = s12 * iv;
    }
    if (kg == 1 && inB) row_count[r] = 0;

    if (wplanes) {
        // fragment-major LDS stash: slot kg, hw from j>=8, fr*4 + pair idx
        const int i0 = kg * 256 + fr * 4;
        #pragma unroll
        for (int i = 0; i < 4; i++) {
            union { _Float16 h[2]; unsigned u; } hh, ll;
            hh.h[0] = (_Float16)a[2*i];     ll.h[0] = (_Float16)(a[2*i]     - (float)hh.h[0]);
            hh.h[1] = (_Float16)a[2*i+1];   ll.h[1] = (_Float16)(a[2*i+1]   - (float)hh.h[1]);
            s1h[i0 + i] = hh.u;  s1l[i0 + i] = ll.u;
        }
        #pragma unroll
        for (int i = 4; i < 8; i++) {
            union { _Float16 h[2]; unsigned u; } hh, ll;
            hh.h[0] = (_Float16)a[2*i];     ll.h[0] = (_Float16)(a[2*i]     - (float)hh.h[0]);
            hh.h[1] = (_Float16)a[2*i+1];   ll.h[1] = (_Float16)(a[2*i+1]   - (float)hh.h[1]);
            s1h[i0 + 128 + i - 4] = hh.u;  s1l[i0 + 128 + i - 4] = ll.u;
        }
        #pragma unroll
        for (int i = 0; i < 4; i++) {
            union { _Float16 h[2]; unsigned u; } hh, ll;
            hh.h[0] = (_Float16)b[2*i];     ll.h[0] = (_Float16)(b[2*i]     - (float)hh.h[0]);
            hh.h[1] = (_Float16)b[2*i+1];   ll.h[1] = (_Float16)(b[2*i+1]   - (float)hh.h[1]);
            s2h[i0 + i] = hh.u;  s2l[i0 + i] = ll.u;
        }
        #pragma unroll
        for (int i = 4; i < 8; i++) {
            union { _Float16 h[2]; unsigned u; } hh, ll;
            hh.h[0] = (_Float16)b[2*i];     ll.h[0] = (_Float16)(b[2*i]     - (float)hh.h[0]);
            hh.h[1] = (_Float16)b[2*i+1];   ll.h[1] = (_Float16)(b[2*i+1]   - (float)hh.h[1]);
            s2h[i0 + 128 + i - 4] = hh.u;  s2l[i0 + 128 + i - 4] = ll.u;
        }
        __syncthreads();
        // coalesced writeout: thread tid covers u32s [tid*8, tid*8+8)
        const size_t gb = (size_t)(row0 >> 5) * 2048 + (size_t)tid * 8;
        const int lb = tid * 8;
        if (row0 < B) {    // 32|B in fast path -> whole superblock valid
            *(uint4*)&x1h[gb]     = *(const uint4*)&s1h[lb];
            *(uint4*)&x1h[gb + 4] = *(const uint4*)&s1h[lb + 4];
            *(uint4*)&x1l[gb]     = *(const uint4*)&s1l[lb];
            *(uint4*)&x1l[gb + 4] = *(const uint4*)&s1l[lb + 4];
        }
        if (row0 < S) {
            *(uint4*)&x2h[gb]     = *(const uint4*)&s2h[lb];
            *(uint4*)&x2h[gb + 4] = *(const uint4*)&s2h[lb + 4];
            *(uint4*)&x2l[gb]     = *(const uint4*)&s2l[lb];
            *(uint4*)&x2l[gb + 4] = *(const uint4*)&s2l[lb + 4];
        }
    }
}

// ---------- Kernel B (fast): zero-LDS zero-barrier L2-streamed fp16x3 GEMM + count ----------
// Block = 128x128 (4 waves, 2x2 of 64x64 wave tiles). R4 structure verbatim;
// launch_bounds(256,8) requests 8 blocks/CU. Last-done block computes the
// final mean (finalize merged).
__global__ __launch_bounds__(256, 8) void count_kernel_fast(
    const _Float16* __restrict__ x1h, const _Float16* __restrict__ x1l,
    const _Float16* __restrict__ x2h, const _Float16* __restrict__ x2l,
    const float* __restrict__ invn, const float* __restrict__ thr,
    int* __restrict__ row_count, unsigned* __restrict__ done,
    float* __restrict__ out, int B, int nper)
{
    __shared__ float s_thr[128], s_invn[128];
    __shared__ int cnt_s[128];
    __shared__ int s_red[5];        // [0..3] wave sums, [4] is_last flag

    const int tid  = threadIdx.x;
    const int wave = tid >> 6;
    const int lane = tid & 63;
    const int row0 = blockIdx.y * 128;
    const int col0 = blockIdx.x * 128;
    const int wr = (wave >> 1) * 64;   // wave row offset
    const int wc = (wave & 1) * 64;    // wave col offset

    if (tid < 128) {
        cnt_s[tid]  = 0;
        s_thr[tid]  = thr[row0 + tid];
        s_invn[tid] = invn[col0 + tid];
    }

    // per-wave fragment stream bases (lane-contiguous 16B within 1KB blocks)
    const size_t la8 = (size_t)lane * 8;
    const _Float16* pah = x1h + (size_t)((row0 + wr) >> 5) * 4096 + la8;
    const _Float16* pal = x1l + (size_t)((row0 + wr) >> 5) * 4096 + la8;
    const _Float16* pbh = x2h + (size_t)((col0 + wc) >> 5) * 4096 + la8;
    const _Float16* pbl = x2l + (size_t)((col0 + wc) >> 5) * 4096 + la8;

    floatx16 acc[2][2];
    #pragma unroll
    for (int a = 0; a < 2; a++)
        #pragma unroll
        for (int b = 0; b < 2; b++)
            #pragma unroll
            for (int i = 0; i < 16; i++) acc[a][b][i] = 0.f;

    // ---- barrier-free MFMA sweep: 8 K16-steps x {8 coalesced loads + 12 MFMAs} ----
    #pragma unroll
    for (int c = 0; c < 4; c++) {
        #pragma unroll
        for (int k2 = 0; k2 < 2; k2++) {
            const int so = (c * 2 + k2) * 512;
            half8 ah[2], al[2], bh[2], bl[2];
            #pragma unroll
            for (int u = 0; u < 2; u++) {
                ah[u] = *(const half8*)(pah + (size_t)u * 4096 + so);
                al[u] = *(const half8*)(pal + (size_t)u * 4096 + so);
                bh[u] = *(const half8*)(pbh + (size_t)u * 4096 + so);
                bl[u] = *(const half8*)(pbl + (size_t)u * 4096 + so);
            }
            #pragma unroll
            for (int mt = 0; mt < 2; mt++)
                #pragma unroll
                for (int nt = 0; nt < 2; nt++) {
                    acc[mt][nt] = __builtin_amdgcn_mfma_f32_32x32x16_f16(al[mt], bh[nt], acc[mt][nt], 0, 0, 0);
                    acc[mt][nt] = __builtin_amdgcn_mfma_f32_32x32x16_f16(ah[mt], bl[nt], acc[mt][nt], 0, 0, 0);
                    acc[mt][nt] = __builtin_amdgcn_mfma_f32_32x32x16_f16(ah[mt], bh[nt], acc[mt][nt], 0, 0, 0);
                }
        }
    }

    __syncthreads();   // s_thr/s_invn/cnt_s init visible to all waves

    // ---- epilogue: normalize, compare vs diag threshold, ballot-count ----
    // C/D layout (32x32): col = lane&31, row = (reg&3) + 8*(reg>>2) + 4*(lane>>5)
    const int cm = lane & 31;
    const int hw = lane >> 5;
    const float iv0 = s_invn[wc + cm];
    const float iv1 = s_invn[wc + 32 + cm];
    const int gc0 = col0 + wc + cm;
    const int gc1 = gc0 + 32;

    #pragma unroll
    for (int mt = 0; mt < 2; mt++) {
        #pragma unroll
        for (int reg = 0; reg < 16; reg++) {
            const int rbase = wr + mt * 32 + (reg & 3) + 8 * (reg >> 2);
            const int rloc  = rbase + 4 * hw;
            const int grow  = row0 + rloc;
            const float t   = s_thr[rloc];
            const bool p0 = (acc[mt][0][reg] * iv0 > t) && (gc0 != grow);
            const bool p1 = (acc[mt][1][reg] * iv1 > t) && (gc1 != grow);
            const unsigned long long b0 = __ballot(p0);
            const unsigned long long b1 = __ballot(p1);
            if (lane == 0) {
                const int clo = __popcll(b0 & 0xffffffffULL) + __popcll(b1 & 0xffffffffULL);
                if (clo) atomicAdd(&cnt_s[rbase], clo);
            } else if (lane == 32) {
                const int chi = __popcll(b0 >> 32) + __popcll(b1 >> 32);
                if (chi) atomicAdd(&cnt_s[rbase + 4], chi);
            }
        }
    }
    __syncthreads();
    if (tid < 128) {
        const int v = cnt_s[tid];
        if (v) atomicAdd(&row_count[row0 + tid], v);
    }

    // ---- merged finalize: last-done block reduces row_count -> out ----
    __threadfence();      // order this block's row_count atomics
    __syncthreads();      // barrier drains vmcnt -> atomics complete
    if (tid == 0) {
        const unsigned total = gridDim.x * gridDim.y;
        s_red[4] = (atomicAdd(done, 1u) == total - 1u) ? 1 : 0;
    }
    __syncthreads();
    if (s_red[4]) {       // uniform across block
        int c = 0;
        for (int i = tid; i < B; i += 256)
            c += (atomicAdd(&row_count[i], 0) < nper) ? 1 : 0;   // coherent read
        #pragma unroll
        for (int m = 32; m > 0; m >>= 1) c += __shfl_xor(c, m);
        if (lane == 0) s_red[wave] = c;
        __syncthreads();
        if (tid == 0)
            out[0] = (float)(s_red[0] + s_red[1] + s_red[2] + s_red[3]) / (float)B;
    }
}

// ---------- Kernel B (fallback, proven): in-kernel conversion path ----------
__global__ __launch_bounds__(256) void count_kernel_conv(
    const float* __restrict__ x1, const float* __restrict__ x2,
    const float* __restrict__ invn, const float* __restrict__ thr,
    int* __restrict__ row_count)
{
    __shared__ __align__(16) _Float16 As_hi[4096], As_lo[4096];
    __shared__ __align__(16) _Float16 Bs_hi[4096], Bs_lo[4096];
    __shared__ float s_thr[128], s_invn[128];
    __shared__ int cnt_s[128];

    const int tid  = threadIdx.x;
    const int wave = tid >> 6;
    const int lane = tid & 63;
    const int row0 = blockIdx.y * 128;
    const int col0 = blockIdx.x * 128;
    const int wr = (wave >> 1) * 64;
    const int wc = (wave & 1) * 64;

    if (tid < 128) {
        cnt_s[tid]  = 0;
        s_thr[tid]  = thr[row0 + tid];
        s_invn[tid] = invn[col0 + tid];
    }

    floatx16 acc[2][2];
    #pragma unroll
    for (int a = 0; a < 2; a++)
        #pragma unroll
        for (int b = 0; b < 2; b++)
            #pragma unroll
            for (int i = 0; i < 16; i++) acc[a][b][i] = 0.f;

    const int sr   = tid >> 1;
    const int sks2 = tid & 1;
    const int wbase = ((sr >> 5) * 2 + sks2) * 512 + (sr & 31) * 8;
    const size_t ga = (size_t)(row0 + sr) * KDIM + sks2 * 16;
    const size_t gb = (size_t)(col0 + sr) * KDIM + sks2 * 16;

    const int wrg = wr >> 5;
    const int wcg = wc >> 5;
    const int lane8 = lane * 8;

    for (int kc = 0; kc < KDIM; kc += 32) {
        __syncthreads();
        {
            const float* p = &x1[ga + kc];
            float v[16];
            *(float4*)&v[0]  = *(const float4*)(p);
            *(float4*)&v[4]  = *(const float4*)(p + 4);
            *(float4*)&v[8]  = *(const float4*)(p + 8);
            *(float4*)&v[12] = *(const float4*)(p + 12);
            half8 h0, h1, l0, l1;
            #pragma unroll
            for (int i = 0; i < 8; i++) {
                _Float16 h = (_Float16)v[i];
                h0[i] = h; l0[i] = (_Float16)(v[i] - (float)h);
                _Float16 g = (_Float16)v[i + 8];
                h1[i] = g; l1[i] = (_Float16)(v[i + 8] - (float)g);
            }
            *(half8*)&As_hi[wbase]       = h0;
            *(half8*)&As_hi[wbase + 256] = h1;
            *(half8*)&As_lo[wbase]       = l0;
            *(half8*)&As_lo[wbase + 256] = l1;
        }
        {
            const float* p = &x2[gb + kc];
            float v[16];
            *(float4*)&v[0]  = *(const float4*)(p);
            *(float4*)&v[4]  = *(const float4*)(p + 4);
            *(float4*)&v[8]  = *(const float4*)(p + 8);
            *(float4*)&v[12] = *(const float4*)(p + 12);
            half8 h0, h1, l0, l1;
            #pragma unroll
            for (int i = 0; i < 8; i++) {
                _Float16 h = (_Float16)v[i];
                h0[i] = h; l0[i] = (_Float16)(v[i] - (float)h);
                _Float16 g = (_Float16)v[i + 8];
                h1[i] = g; l1[i] = (_Float16)(v[i + 8] - (float)g);
            }
            *(half8*)&Bs_hi[wbase]       = h0;
            *(half8*)&Bs_hi[wbase + 256] = h1;
            *(half8*)&Bs_lo[wbase]       = l0;
            *(half8*)&Bs_lo[wbase + 256] = l1;
        }
        __syncthreads();

        #pragma unroll
        for (int ks2 = 0; ks2 < 2; ks2++) {
            half8 ah[2], al[2], bh[2], bl[2];
            #pragma unroll
            for (int t = 0; t < 2; t++) {
                const int oa = ((wrg + t) * 2 + ks2) * 512 + lane8;
                ah[t] = *(const half8*)&As_hi[oa];
                al[t] = *(const half8*)&As_lo[oa];
                const int ob = ((wcg + t) * 2 + ks2) * 512 + lane8;
                bh[t] = *(const half8*)&Bs_hi[ob];
                bl[t] = *(const half8*)&Bs_lo[ob];
            }
            #pragma unroll
            for (int mt = 0; mt < 2; mt++)
                #pragma unroll
                for (int nt = 0; nt < 2; nt++) {
                    acc[mt][nt] = __builtin_amdgcn_mfma_f32_32x32x16_f16(al[mt], bh[nt], acc[mt][nt], 0, 0, 0);
                    acc[mt][nt] = __builtin_amdgcn_mfma_f32_32x32x16_f16(ah[mt], bl[nt], acc[mt][nt], 0, 0, 0);
                    acc[mt][nt] = __builtin_amdgcn_mfma_f32_32x32x16_f16(ah[mt], bh[nt], acc[mt][nt], 0, 0, 0);
                }
        }
    }

    const int cm = lane & 31;
    const int hw = lane >> 5;
    const float iv0 = s_invn[wc + cm];
    const float iv1 = s_invn[wc + 32 + cm];
    const int gc0 = col0 + wc + cm;
    const int gc1 = gc0 + 32;

    #pragma unroll
    for (int mt = 0; mt < 2; mt++) {
        #pragma unroll
        for (int reg = 0; reg < 16; reg++) {
            const int rbase = wr + mt * 32 + (reg & 3) + 8 * (reg >> 2);
            const int rloc  = rbase + 4 * hw;
            const int grow  = row0 + rloc;
            const float t   = s_thr[rloc];
            const bool p0 = (acc[mt][0][reg] * iv0 > t) && (gc0 != grow);
            const bool p1 = (acc[mt][1][reg] * iv1 > t) && (gc1 != grow);
            const unsigned long long b0 = __ballot(p0);
            const unsigned long long b1 = __ballot(p1);
            if (lane == 0) {
                const int clo = __popcll(b0 & 0xffffffffULL) + __popcll(b1 & 0xffffffffULL);
                if (clo) atomicAdd(&cnt_s[rbase], clo);
            } else if (lane == 32) {
                const int chi = __popcll(b0 >> 32) + __popcll(b1 >> 32);
                if (chi) atomicAdd(&cnt_s[rbase + 4], chi);
            }
        }
    }
    __syncthreads();
    if (tid < 128) {
        const int v = cnt_s[tid];
        if (v) atomicAdd(&row_count[row0 + tid], v);
    }
}

// ---------- Kernel C: final reduction (fallback path only) ----------
__global__ __launch_bounds__(1024) void finalize_kernel(
    const int* __restrict__ row_count, float* __restrict__ out, int B, int nper)
{
    __shared__ int wsum[16];
    const int t = threadIdx.x;
    int c = 0;
    for (int i = t; i < B; i += 1024) c += (row_count[i] < nper) ? 1 : 0;
    #pragma unroll
    for (int m = 32; m > 0; m >>= 1) c += __shfl_xor(c, m);
    if ((t & 63) == 0) wsum[t >> 6] = c;
    __syncthreads();
    if (t == 0) {
        int tot = 0;
        #pragma unroll
        for (int w = 0; w < 16; w++) tot += wsum[w];
        out[0] = (float)tot / (float)B;
    }
}

extern "C" void kernel_launch(void* const* d_in, const int* in_sizes, int n_in,
                              void* d_out, int out_size, void* d_ws, size_t ws_size,
                              hipStream_t stream)
{
    const float* x1 = (const float*)d_in[0];
    const float* x2 = (const float*)d_in[1];
    const int B = in_sizes[0] / KDIM;     // 8192
    const int S = in_sizes[1] / KDIM;     // 8192
    const int nper = S / 100 + 1;         // 82

    float* invn      = (float*)d_ws;
    float* thr       = invn + S;
    int*   row_count = (int*)(thr + B);
    unsigned* done   = (unsigned*)(row_count + B);

    uintptr_t ap = ((uintptr_t)(done + 4) + 15) & ~(uintptr_t)15;
    _Float16* x1h = (_Float16*)ap;
    _Float16* x1l = x1h + (size_t)B * KDIM;
    _Float16* x2h = x1l + (size_t)B * KDIM;
    _Float16* x2l = x2h + (size_t)S * KDIM;
    const size_t need = (size_t)((char*)(x2l + (size_t)S * KDIM) - (char*)d_ws);
    // fast path: ws for planes + 128-divisible dims (fragment-major superblocks)
    const int fast = (ws_size >= need && (B % 128) == 0 && (S % 128) == 0) ? 1 : 0;

    const int mx = (B > S) ? B : S;
    prep_kernel<<<(mx + 31) / 32, 256, 0, stream>>>(
        x1, x2, invn, thr, row_count, done,
        (unsigned*)x1h, (unsigned*)x1l, (unsigned*)x2h, (unsigned*)x2l,
        B, S, fast);

    if (fast) {
        dim3 grid(S / 128, B / 128);
        count_kernel_fast<<<grid, 256, 0, stream>>>(
            x1h, x1l, x2h, x2l, invn, thr, row_count, done,
            (float*)d_out, B, nper);
        // finalize merged into count (last-done block)
    } else {
        dim3 grid(S / 128, B / 128);
        count_kernel_conv<<<grid, 256, 0, stream>>>(x1, x2, invn, thr, row_count);
        finalize_kernel<<<1, 1024, 0, stream>>>(row_count, (float*)d_out, B, nper);
    }
}

// Round 8
// 379.262 us; speedup vs baseline: 3.9116x; 3.9116x over previous
//
#include <hip/hip_runtime.h>

// out = mean_i( rank_of_diag(cos_sim(x1,x2))_i < nper ), nper = S/100+1.
// rank_i = #{ j != i : dot(x1_i,x2_j)*inv||x2_j|| > dot(x1_i,x2_i)*inv||x2_i|| }
// GEMM via fp16x3 (Markidis split) MFMA: x=hi+lo; hi*hi + hi*lo + lo*hi.
// Dropped lo*lo ~2^-22 rel/term -> dot err ~3e-6 << 4.5e-3 order-stat spacing.
//
// R8: revert count to R4's proven structure (zero-LDS zero-barrier streamed,
// launch_bounds(256,3) -> VGPR~64, 69us). R7's launch_bounds(256,8) forced a
// 64-reg cap and spilled the accumulators to scratch (VGPR=32, 3.5GB scratch
// traffic, 1465us). Kept from R7 (both verified correct): merged last-block
// finalize (device-scope done counter) and coalesced LDS-staged prep.
//
// Fragment-major plane layout (per plane, halves):
//   addr(row,k) = (row>>5)*4096 + ((k>>5)*2 + ((k>>4)&1))*512
//               + ((k>>3)&1)*256 + (row&31)*8 + (k&7)
// -> 32-row x 16-half fragment = contiguous 1KB, lane reads 16B at +lane*8.

#define KDIM 128

typedef _Float16 half8 __attribute__((ext_vector_type(8)));
typedef float floatx16 __attribute__((ext_vector_type(16)));

// ---------- Kernel A: norms/threshold + coalesced fragment-major fp16 planes ----------
// 256 thr / 32 rows per block; thread (fr=tid>>3, kg=tid&7) owns 16 floats of
// row fr. hi/lo conversion staged in LDS in fragment order, then written out
// as contiguous uint4 streams (fully coalesced).
__global__ __launch_bounds__(256) void prep_kernel(
    const float* __restrict__ x1, const float* __restrict__ x2,
    float* __restrict__ invn, float* __restrict__ thr,
    int* __restrict__ row_count, unsigned* __restrict__ done,
    unsigned* __restrict__ x1h, unsigned* __restrict__ x1l,
    unsigned* __restrict__ x2h, unsigned* __restrict__ x2l,
    int B, int S, int wplanes)
{
    __shared__ __align__(16) unsigned s1h[2048], s1l[2048], s2h[2048], s2l[2048];
    const int tid  = threadIdx.x;
    const int row0 = blockIdx.x * 32;
    const int fr   = tid >> 3;          // row within superblock (0..31)
    const int kg   = tid & 7;           // k16-group (0..7)
    const int r    = row0 + fr;

    if (blockIdx.x == 0 && tid == 0) *done = 0u;

    const bool inB = (r < B);
    const bool inS = (r < S);

    float a[16], b[16];
    float s22 = 0.f, s12 = 0.f;
    if (inB) {
        const float4* p = (const float4*)&x1[(size_t)r * KDIM + kg * 16];
        *(float4*)&a[0]  = p[0];
        *(float4*)&a[4]  = p[1];
        *(float4*)&a[8]  = p[2];
        *(float4*)&a[12] = p[3];
    } else {
        #pragma unroll
        for (int i = 0; i < 16; i++) a[i] = 0.f;
    }
    if (inS) {
        const float4* p = (const float4*)&x2[(size_t)r * KDIM + kg * 16];
        *(float4*)&b[0]  = p[0];
        *(float4*)&b[4]  = p[1];
        *(float4*)&b[8]  = p[2];
        *(float4*)&b[12] = p[3];
        #pragma unroll
        for (int i = 0; i < 16; i++) {
            s22 = fmaf(b[i], b[i], s22);
            s12 = fmaf(a[i], b[i], s12);
        }
    } else {
        #pragma unroll
        for (int i = 0; i < 16; i++) b[i] = 0.f;
    }
    // reduce across the 8 threads of this row (contiguous lanes)
    #pragma unroll
    for (int m = 1; m <= 4; m <<= 1) {
        s22 += __shfl_xor(s22, m);
        s12 += __shfl_xor(s12, m);
    }
    if (kg == 0 && inS) {
        const float iv = rsqrtf(s22);
        invn[r] = iv;
        if (inB) thr[r] = s12 * iv;
    }
    if (kg == 1 && inB) row_count[r] = 0;

    if (wplanes) {
        // fragment-major LDS stash
        const int i0 = kg * 256 + fr * 4;
        #pragma unroll
        for (int i = 0; i < 4; i++) {
            union { _Float16 h[2]; unsigned u; } hh, ll;
            hh.h[0] = (_Float16)a[2*i];     ll.h[0] = (_Float16)(a[2*i]     - (float)hh.h[0]);
            hh.h[1] = (_Float16)a[2*i+1];   ll.h[1] = (_Float16)(a[2*i+1]   - (float)hh.h[1]);
            s1h[i0 + i] = hh.u;  s1l[i0 + i] = ll.u;
        }
        #pragma unroll
        for (int i = 4; i < 8; i++) {
            union { _Float16 h[2]; unsigned u; } hh, ll;
            hh.h[0] = (_Float16)a[2*i];     ll.h[0] = (_Float16)(a[2*i]     - (float)hh.h[0]);
            hh.h[1] = (_Float16)a[2*i+1];   ll.h[1] = (_Float16)(a[2*i+1]   - (float)hh.h[1]);
            s1h[i0 + 128 + i - 4] = hh.u;  s1l[i0 + 128 + i - 4] = ll.u;
        }
        #pragma unroll
        for (int i = 0; i < 4; i++) {
            union { _Float16 h[2]; unsigned u; } hh, ll;
            hh.h[0] = (_Float16)b[2*i];     ll.h[0] = (_Float16)(b[2*i]     - (float)hh.h[0]);
            hh.h[1] = (_Float16)b[2*i+1];   ll.h[1] = (_Float16)(b[2*i+1]   - (float)hh.h[1]);
            s2h[i0 + i] = hh.u;  s2l[i0 + i] = ll.u;
        }
        #pragma unroll
        for (int i = 4; i < 8; i++) {
            union { _Float16 h[2]; unsigned u; } hh, ll;
            hh.h[0] = (_Float16)b[2*i];     ll.h[0] = (_Float16)(b[2*i]     - (float)hh.h[0]);
            hh.h[1] = (_Float16)b[2*i+1];   ll.h[1] = (_Float16)(b[2*i+1]   - (float)hh.h[1]);
            s2h[i0 + 128 + i - 4] = hh.u;  s2l[i0 + 128 + i - 4] = ll.u;
        }
        __syncthreads();
        // coalesced writeout: thread tid covers u32s [tid*8, tid*8+8)
        const size_t gb = (size_t)(row0 >> 5) * 2048 + (size_t)tid * 8;
        const int lb = tid * 8;
        if (row0 < B) {
            *(uint4*)&x1h[gb]     = *(const uint4*)&s1h[lb];
            *(uint4*)&x1h[gb + 4] = *(const uint4*)&s1h[lb + 4];
            *(uint4*)&x1l[gb]     = *(const uint4*)&s1l[lb];
            *(uint4*)&x1l[gb + 4] = *(const uint4*)&s1l[lb + 4];
        }
        if (row0 < S) {
            *(uint4*)&x2h[gb]     = *(const uint4*)&s2h[lb];
            *(uint4*)&x2h[gb + 4] = *(const uint4*)&s2h[lb + 4];
            *(uint4*)&x2l[gb]     = *(const uint4*)&s2l[lb];
            *(uint4*)&x2l[gb + 4] = *(const uint4*)&s2l[lb + 4];
        }
    }
}

// ---------- Kernel B (fast): zero-LDS zero-barrier L2-streamed fp16x3 GEMM + count ----------
// R4 structure verbatim: block = 128x128 (4 waves, 2x2 of 64x64 wave tiles),
// launch_bounds(256,3). Last-done block computes the final mean.
__global__ __launch_bounds__(256, 3) void count_kernel_fast(
    const _Float16* __restrict__ x1h, const _Float16* __restrict__ x1l,
    const _Float16* __restrict__ x2h, const _Float16* __restrict__ x2l,
    const float* __restrict__ invn, const float* __restrict__ thr,
    int* __restrict__ row_count, unsigned* __restrict__ done,
    float* __restrict__ out, int B, int nper)
{
    __shared__ float s_thr[128], s_invn[128];
    __shared__ int cnt_s[128];
    __shared__ int s_red[5];        // [0..3] wave sums, [4] is_last flag

    const int tid  = threadIdx.x;
    const int wave = tid >> 6;
    const int lane = tid & 63;
    const int row0 = blockIdx.y * 128;
    const int col0 = blockIdx.x * 128;
    const int wr = (wave >> 1) * 64;   // wave row offset
    const int wc = (wave & 1) * 64;    // wave col offset

    if (tid < 128) {
        cnt_s[tid]  = 0;
        s_thr[tid]  = thr[row0 + tid];
        s_invn[tid] = invn[col0 + tid];
    }

    // per-wave fragment stream bases (lane-contiguous 16B within 1KB blocks)
    const size_t la8 = (size_t)lane * 8;
    const _Float16* pah = x1h + (size_t)((row0 + wr) >> 5) * 4096 + la8;
    const _Float16* pal = x1l + (size_t)((row0 + wr) >> 5) * 4096 + la8;
    const _Float16* pbh = x2h + (size_t)((col0 + wc) >> 5) * 4096 + la8;
    const _Float16* pbl = x2l + (size_t)((col0 + wc) >> 5) * 4096 + la8;

    floatx16 acc[2][2];
    #pragma unroll
    for (int a = 0; a < 2; a++)
        #pragma unroll
        for (int b = 0; b < 2; b++)
            #pragma unroll
            for (int i = 0; i < 16; i++) acc[a][b][i] = 0.f;

    // ---- barrier-free MFMA sweep: 8 K16-steps x {8 coalesced loads + 12 MFMAs} ----
    #pragma unroll
    for (int c = 0; c < 4; c++) {
        #pragma unroll
        for (int k2 = 0; k2 < 2; k2++) {
            const int so = (c * 2 + k2) * 512;
            half8 ah[2], al[2], bh[2], bl[2];
            #pragma unroll
            for (int u = 0; u < 2; u++) {
                ah[u] = *(const half8*)(pah + (size_t)u * 4096 + so);
                al[u] = *(const half8*)(pal + (size_t)u * 4096 + so);
                bh[u] = *(const half8*)(pbh + (size_t)u * 4096 + so);
                bl[u] = *(const half8*)(pbl + (size_t)u * 4096 + so);
            }
            #pragma unroll
            for (int mt = 0; mt < 2; mt++)
                #pragma unroll
                for (int nt = 0; nt < 2; nt++) {
                    acc[mt][nt] = __builtin_amdgcn_mfma_f32_32x32x16_f16(al[mt], bh[nt], acc[mt][nt], 0, 0, 0);
                    acc[mt][nt] = __builtin_amdgcn_mfma_f32_32x32x16_f16(ah[mt], bl[nt], acc[mt][nt], 0, 0, 0);
                    acc[mt][nt] = __builtin_amdgcn_mfma_f32_32x32x16_f16(ah[mt], bh[nt], acc[mt][nt], 0, 0, 0);
                }
        }
    }

    __syncthreads();   // s_thr/s_invn/cnt_s init visible to all waves

    // ---- epilogue: normalize, compare vs diag threshold, ballot-count ----
    // C/D layout (32x32): col = lane&31, row = (reg&3) + 8*(reg>>2) + 4*(lane>>5)
    const int cm = lane & 31;
    const int hw = lane >> 5;
    const float iv0 = s_invn[wc + cm];
    const float iv1 = s_invn[wc + 32 + cm];
    const int gc0 = col0 + wc + cm;
    const int gc1 = gc0 + 32;

    #pragma unroll
    for (int mt = 0; mt < 2; mt++) {
        #pragma unroll
        for (int reg = 0; reg < 16; reg++) {
            const int rbase = wr + mt * 32 + (reg & 3) + 8 * (reg >> 2);
            const int rloc  = rbase + 4 * hw;
            const int grow  = row0 + rloc;
            const float t   = s_thr[rloc];
            const bool p0 = (acc[mt][0][reg] * iv0 > t) && (gc0 != grow);
            const bool p1 = (acc[mt][1][reg] * iv1 > t) && (gc1 != grow);
            const unsigned long long b0 = __ballot(p0);
            const unsigned long long b1 = __ballot(p1);
            if (lane == 0) {
                const int clo = __popcll(b0 & 0xffffffffULL) + __popcll(b1 & 0xffffffffULL);
                if (clo) atomicAdd(&cnt_s[rbase], clo);
            } else if (lane == 32) {
                const int chi = __popcll(b0 >> 32) + __popcll(b1 >> 32);
                if (chi) atomicAdd(&cnt_s[rbase + 4], chi);
            }
        }
    }
    __syncthreads();
    if (tid < 128) {
        const int v = cnt_s[tid];
        if (v) atomicAdd(&row_count[row0 + tid], v);
    }

    // ---- merged finalize: last-done block reduces row_count -> out ----
    __threadfence();      // order this block's row_count atomics (device scope)
    __syncthreads();
    if (tid == 0) {
        const unsigned total = gridDim.x * gridDim.y;
        s_red[4] = (atomicAdd(done, 1u) == total - 1u) ? 1 : 0;
    }
    __syncthreads();
    if (s_red[4]) {       // uniform across block
        int c = 0;
        for (int i = tid; i < B; i += 256)
            c += (atomicAdd(&row_count[i], 0) < nper) ? 1 : 0;   // coherent read
        #pragma unroll
        for (int m = 32; m > 0; m >>= 1) c += __shfl_xor(c, m);
        if (lane == 0) s_red[wave] = c;
        __syncthreads();
        if (tid == 0)
            out[0] = (float)(s_red[0] + s_red[1] + s_red[2] + s_red[3]) / (float)B;
    }
}

// ---------- Kernel B (fallback, proven): in-kernel conversion path ----------
__global__ __launch_bounds__(256) void count_kernel_conv(
    const float* __restrict__ x1, const float* __restrict__ x2,
    const float* __restrict__ invn, const float* __restrict__ thr,
    int* __restrict__ row_count)
{
    __shared__ __align__(16) _Float16 As_hi[4096], As_lo[4096];
    __shared__ __align__(16) _Float16 Bs_hi[4096], Bs_lo[4096];
    __shared__ float s_thr[128], s_invn[128];
    __shared__ int cnt_s[128];

    const int tid  = threadIdx.x;
    const int wave = tid >> 6;
    const int lane = tid & 63;
    const int row0 = blockIdx.y * 128;
    const int col0 = blockIdx.x * 128;
    const int wr = (wave >> 1) * 64;
    const int wc = (wave & 1) * 64;

    if (tid < 128) {
        cnt_s[tid]  = 0;
        s_thr[tid]  = thr[row0 + tid];
        s_invn[tid] = invn[col0 + tid];
    }

    floatx16 acc[2][2];
    #pragma unroll
    for (int a = 0; a < 2; a++)
        #pragma unroll
        for (int b = 0; b < 2; b++)
            #pragma unroll
            for (int i = 0; i < 16; i++) acc[a][b][i] = 0.f;

    const int sr   = tid >> 1;
    const int sks2 = tid & 1;
    const int wbase = ((sr >> 5) * 2 + sks2) * 512 + (sr & 31) * 8;
    const size_t ga = (size_t)(row0 + sr) * KDIM + sks2 * 16;
    const size_t gb = (size_t)(col0 + sr) * KDIM + sks2 * 16;

    const int wrg = wr >> 5;
    const int wcg = wc >> 5;
    const int lane8 = lane * 8;

    for (int kc = 0; kc < KDIM; kc += 32) {
        __syncthreads();
        {
            const float* p = &x1[ga + kc];
            float v[16];
            *(float4*)&v[0]  = *(const float4*)(p);
            *(float4*)&v[4]  = *(const float4*)(p + 4);
            *(float4*)&v[8]  = *(const float4*)(p + 8);
            *(float4*)&v[12] = *(const float4*)(p + 12);
            half8 h0, h1, l0, l1;
            #pragma unroll
            for (int i = 0; i < 8; i++) {
                _Float16 h = (_Float16)v[i];
                h0[i] = h; l0[i] = (_Float16)(v[i] - (float)h);
                _Float16 g = (_Float16)v[i + 8];
                h1[i] = g; l1[i] = (_Float16)(v[i + 8] - (float)g);
            }
            *(half8*)&As_hi[wbase]       = h0;
            *(half8*)&As_hi[wbase + 256] = h1;
            *(half8*)&As_lo[wbase]       = l0;
            *(half8*)&As_lo[wbase + 256] = l1;
        }
        {
            const float* p = &x2[gb + kc];
            float v[16];
            *(float4*)&v[0]  = *(const float4*)(p);
            *(float4*)&v[4]  = *(const float4*)(p + 4);
            *(float4*)&v[8]  = *(const float4*)(p + 8);
            *(float4*)&v[12] = *(const float4*)(p + 12);
            half8 h0, h1, l0, l1;
            #pragma unroll
            for (int i = 0; i < 8; i++) {
                _Float16 h = (_Float16)v[i];
                h0[i] = h; l0[i] = (_Float16)(v[i] - (float)h);
                _Float16 g = (_Float16)v[i + 8];
                h1[i] = g; l1[i] = (_Float16)(v[i + 8] - (float)g);
            }
            *(half8*)&Bs_hi[wbase]       = h0;
            *(half8*)&Bs_hi[wbase + 256] = h1;
            *(half8*)&Bs_lo[wbase]       = l0;
            *(half8*)&Bs_lo[wbase + 256] = l1;
        }
        __syncthreads();

        #pragma unroll
        for (int ks2 = 0; ks2 < 2; ks2++) {
            half8 ah[2], al[2], bh[2], bl[2];
            #pragma unroll
            for (int t = 0; t < 2; t++) {
                const int oa = ((wrg + t) * 2 + ks2) * 512 + lane8;
                ah[t] = *(const half8*)&As_hi[oa];
                al[t] = *(const half8*)&As_lo[oa];
                const int ob = ((wcg + t) * 2 + ks2) * 512 + lane8;
                bh[t] = *(const half8*)&Bs_hi[ob];
                bl[t] = *(const half8*)&Bs_lo[ob];
            }
            #pragma unroll
            for (int mt = 0; mt < 2; mt++)
                #pragma unroll
                for (int nt = 0; nt < 2; nt++) {
                    acc[mt][nt] = __builtin_amdgcn_mfma_f32_32x32x16_f16(al[mt], bh[nt], acc[mt][nt], 0, 0, 0);
                    acc[mt][nt] = __builtin_amdgcn_mfma_f32_32x32x16_f16(ah[mt], bl[nt], acc[mt][nt], 0, 0, 0);
                    acc[mt][nt] = __builtin_amdgcn_mfma_f32_32x32x16_f16(ah[mt], bh[nt], acc[mt][nt], 0, 0, 0);
                }
        }
    }

    const int cm = lane & 31;
    const int hw = lane >> 5;
    const float iv0 = s_invn[wc + cm];
    const float iv1 = s_invn[wc + 32 + cm];
    const int gc0 = col0 + wc + cm;
    const int gc1 = gc0 + 32;

    #pragma unroll
    for (int mt = 0; mt < 2; mt++) {
        #pragma unroll
        for (int reg = 0; reg < 16; reg++) {
            const int rbase = wr + mt * 32 + (reg & 3) + 8 * (reg >> 2);
            const int rloc  = rbase + 4 * hw;
            const int grow  = row0 + rloc;
            const float t   = s_thr[rloc];
            const bool p0 = (acc[mt][0][reg] * iv0 > t) && (gc0 != grow);
            const bool p1 = (acc[mt][1][reg] * iv1 > t) && (gc1 != grow);
            const unsigned long long b0 = __ballot(p0);
            const unsigned long long b1 = __ballot(p1);
            if (lane == 0) {
                const int clo = __popcll(b0 & 0xffffffffULL) + __popcll(b1 & 0xffffffffULL);
                if (clo) atomicAdd(&cnt_s[rbase], clo);
            } else if (lane == 32) {
                const int chi = __popcll(b0 >> 32) + __popcll(b1 >> 32);
                if (chi) atomicAdd(&cnt_s[rbase + 4], chi);
            }
        }
    }
    __syncthreads();
    if (tid < 128) {
        const int v = cnt_s[tid];
        if (v) atomicAdd(&row_count[row0 + tid], v);
    }
}

// ---------- Kernel C: final reduction (fallback path only) ----------
__global__ __launch_bounds__(1024) void finalize_kernel(
    const int* __restrict__ row_count, float* __restrict__ out, int B, int nper)
{
    __shared__ int wsum[16];
    const int t = threadIdx.x;
    int c = 0;
    for (int i = t; i < B; i += 1024) c += (row_count[i] < nper) ? 1 : 0;
    #pragma unroll
    for (int m = 32; m > 0; m >>= 1) c += __shfl_xor(c, m);
    if ((t & 63) == 0) wsum[t >> 6] = c;
    __syncthreads();
    if (t == 0) {
        int tot = 0;
        #pragma unroll
        for (int w = 0; w < 16; w++) tot += wsum[w];
        out[0] = (float)tot / (float)B;
    }
}

extern "C" void kernel_launch(void* const* d_in, const int* in_sizes, int n_in,
                              void* d_out, int out_size, void* d_ws, size_t ws_size,
                              hipStream_t stream)
{
    const float* x1 = (const float*)d_in[0];
    const float* x2 = (const float*)d_in[1];
    const int B = in_sizes[0] / KDIM;     // 8192
    const int S = in_sizes[1] / KDIM;     // 8192
    const int nper = S / 100 + 1;         // 82

    float* invn      = (float*)d_ws;
    float* thr       = invn + S;
    int*   row_count = (int*)(thr + B);
    unsigned* done   = (unsigned*)(row_count + B);

    uintptr_t ap = ((uintptr_t)(done + 4) + 15) & ~(uintptr_t)15;
    _Float16* x1h = (_Float16*)ap;
    _Float16* x1l = x1h + (size_t)B * KDIM;
    _Float16* x2h = x1l + (size_t)B * KDIM;
    _Float16* x2l = x2h + (size_t)S * KDIM;
    const size_t need = (size_t)((char*)(x2l + (size_t)S * KDIM) - (char*)d_ws);
    // fast path: ws for planes + 128-divisible dims (fragment-major superblocks)
    const int fast = (ws_size >= need && (B % 128) == 0 && (S % 128) == 0) ? 1 : 0;

    const int mx = (B > S) ? B : S;
    prep_kernel<<<(mx + 31) / 32, 256, 0, stream>>>(
        x1, x2, invn, thr, row_count, done,
        (unsigned*)x1h, (unsigned*)x1l, (unsigned*)x2h, (unsigned*)x2l,
        B, S, fast);

    if (fast) {
        dim3 grid(S / 128, B / 128);
        count_kernel_fast<<<grid, 256, 0, stream>>>(
            x1h, x1l, x2h, x2l, invn, thr, row_count, done,
            (float*)d_out, B, nper);
        // finalize merged into count (last-done block)
    } else {
        dim3 grid(S / 128, B / 128);
        count_kernel_conv<<<grid, 256, 0, stream>>>(x1, x2, invn, thr, row_count);
        finalize_kernel<<<1, 1024, 0, stream>>>(row_count, (float*)d_out, B, nper);
    }
}

// Round 9
// 125.387 us; speedup vs baseline: 11.8316x; 3.0247x over previous
//
#include <hip/hip_runtime.h>

// out = mean_i( rank_of_diag(cos_sim(x1,x2))_i < nper ), nper = S/100+1.
// rank_i = #{ j != i : dot(x1_i,x2_j)*inv||x2_j|| > dot(x1_i,x2_i)*inv||x2_i|| }
// GEMM via fp16x3 (Markidis split) MFMA: x=hi+lo; hi*hi + hi*lo + lo*hi.
// Dropped lo*lo ~2^-22 rel/term -> dot err ~3e-6 << 4.5e-3 order-stat spacing.
//
// R9: bank the proven best. count = R4 verbatim (zero-LDS zero-barrier
// L2-streamed, launch_bounds(256,3), 69us). prep = R8's coalesced LDS-staged
// plane writer. finalize = separate 1-block kernel.
// R8 lesson (pitfall): per-block __threadfence() in a 4096-block grid lowers
// to an L2 writeback+invalidate (cross-XCD coherence) and poisoned L2 for all
// co-resident blocks -> count 69->339us. Merged finalize removed.
// R7 lesson: launch_bounds(256,8) caps regs at 64 -> acc spills to scratch.
//
// Fragment-major plane layout (per plane, halves):
//   addr(row,k) = (row>>5)*4096 + ((k>>5)*2 + ((k>>4)&1))*512
//               + ((k>>3)&1)*256 + (row&31)*8 + (k&7)
// -> 32-row x 16-half fragment = contiguous 1KB, lane reads 16B at +lane*8.

#define KDIM 128

typedef _Float16 half8 __attribute__((ext_vector_type(8)));
typedef float floatx16 __attribute__((ext_vector_type(16)));

// ---------- Kernel A: norms/threshold + coalesced fragment-major fp16 planes ----------
// 256 thr / 32 rows per block; thread (fr=tid>>3, kg=tid&7) owns 16 floats of
// row fr. hi/lo conversion staged in LDS in fragment order, then written out
// as contiguous uint4 streams (fully coalesced).
__global__ __launch_bounds__(256) void prep_kernel(
    const float* __restrict__ x1, const float* __restrict__ x2,
    float* __restrict__ invn, float* __restrict__ thr,
    int* __restrict__ row_count,
    unsigned* __restrict__ x1h, unsigned* __restrict__ x1l,
    unsigned* __restrict__ x2h, unsigned* __restrict__ x2l,
    int B, int S, int wplanes)
{
    __shared__ __align__(16) unsigned s1h[2048], s1l[2048], s2h[2048], s2l[2048];
    const int tid  = threadIdx.x;
    const int row0 = blockIdx.x * 32;
    const int fr   = tid >> 3;          // row within superblock (0..31)
    const int kg   = tid & 7;           // k16-group (0..7)
    const int r    = row0 + fr;

    const bool inB = (r < B);
    const bool inS = (r < S);

    float a[16], b[16];
    float s22 = 0.f, s12 = 0.f;
    if (inB) {
        const float4* p = (const float4*)&x1[(size_t)r * KDIM + kg * 16];
        *(float4*)&a[0]  = p[0];
        *(float4*)&a[4]  = p[1];
        *(float4*)&a[8]  = p[2];
        *(float4*)&a[12] = p[3];
    } else {
        #pragma unroll
        for (int i = 0; i < 16; i++) a[i] = 0.f;
    }
    if (inS) {
        const float4* p = (const float4*)&x2[(size_t)r * KDIM + kg * 16];
        *(float4*)&b[0]  = p[0];
        *(float4*)&b[4]  = p[1];
        *(float4*)&b[8]  = p[2];
        *(float4*)&b[12] = p[3];
        #pragma unroll
        for (int i = 0; i < 16; i++) {
            s22 = fmaf(b[i], b[i], s22);
            s12 = fmaf(a[i], b[i], s12);
        }
    } else {
        #pragma unroll
        for (int i = 0; i < 16; i++) b[i] = 0.f;
    }
    // reduce across the 8 threads of this row (contiguous lanes)
    #pragma unroll
    for (int m = 1; m <= 4; m <<= 1) {
        s22 += __shfl_xor(s22, m);
        s12 += __shfl_xor(s12, m);
    }
    if (kg == 0 && inS) {
        const float iv = rsqrtf(s22);
        invn[r] = iv;
        if (inB) thr[r] = s12 * iv;
    }
    if (kg == 1 && inB) row_count[r] = 0;

    if (wplanes) {
        // fragment-major LDS stash
        const int i0 = kg * 256 + fr * 4;
        #pragma unroll
        for (int i = 0; i < 4; i++) {
            union { _Float16 h[2]; unsigned u; } hh, ll;
            hh.h[0] = (_Float16)a[2*i];     ll.h[0] = (_Float16)(a[2*i]     - (float)hh.h[0]);
            hh.h[1] = (_Float16)a[2*i+1];   ll.h[1] = (_Float16)(a[2*i+1]   - (float)hh.h[1]);
            s1h[i0 + i] = hh.u;  s1l[i0 + i] = ll.u;
        }
        #pragma unroll
        for (int i = 4; i < 8; i++) {
            union { _Float16 h[2]; unsigned u; } hh, ll;
            hh.h[0] = (_Float16)a[2*i];     ll.h[0] = (_Float16)(a[2*i]     - (float)hh.h[0]);
            hh.h[1] = (_Float16)a[2*i+1];   ll.h[1] = (_Float16)(a[2*i+1]   - (float)hh.h[1]);
            s1h[i0 + 128 + i - 4] = hh.u;  s1l[i0 + 128 + i - 4] = ll.u;
        }
        #pragma unroll
        for (int i = 0; i < 4; i++) {
            union { _Float16 h[2]; unsigned u; } hh, ll;
            hh.h[0] = (_Float16)b[2*i];     ll.h[0] = (_Float16)(b[2*i]     - (float)hh.h[0]);
            hh.h[1] = (_Float16)b[2*i+1];   ll.h[1] = (_Float16)(b[2*i+1]   - (float)hh.h[1]);
            s2h[i0 + i] = hh.u;  s2l[i0 + i] = ll.u;
        }
        #pragma unroll
        for (int i = 4; i < 8; i++) {
            union { _Float16 h[2]; unsigned u; } hh, ll;
            hh.h[0] = (_Float16)b[2*i];     ll.h[0] = (_Float16)(b[2*i]     - (float)hh.h[0]);
            hh.h[1] = (_Float16)b[2*i+1];   ll.h[1] = (_Float16)(b[2*i+1]   - (float)hh.h[1]);
            s2h[i0 + 128 + i - 4] = hh.u;  s2l[i0 + 128 + i - 4] = ll.u;
        }
        __syncthreads();
        // coalesced writeout: thread tid covers u32s [tid*8, tid*8+8)
        const size_t gb = (size_t)(row0 >> 5) * 2048 + (size_t)tid * 8;
        const int lb = tid * 8;
        if (row0 < B) {
            *(uint4*)&x1h[gb]     = *(const uint4*)&s1h[lb];
            *(uint4*)&x1h[gb + 4] = *(const uint4*)&s1h[lb + 4];
            *(uint4*)&x1l[gb]     = *(const uint4*)&s1l[lb];
            *(uint4*)&x1l[gb + 4] = *(const uint4*)&s1l[lb + 4];
        }
        if (row0 < S) {
            *(uint4*)&x2h[gb]     = *(const uint4*)&s2h[lb];
            *(uint4*)&x2h[gb + 4] = *(const uint4*)&s2h[lb + 4];
            *(uint4*)&x2l[gb]     = *(const uint4*)&s2l[lb];
            *(uint4*)&x2l[gb + 4] = *(const uint4*)&s2l[lb + 4];
        }
    }
}

// ---------- Kernel B (fast): zero-LDS zero-barrier L2-streamed fp16x3 GEMM + count ----------
// R4 verbatim. Block = 128x128 (4 waves, 2x2 of 64x64 wave tiles); every
// fragment streamed from the fragment-major planes; no fences, no LDS tiles.
__global__ __launch_bounds__(256, 3) void count_kernel_fast(
    const _Float16* __restrict__ x1h, const _Float16* __restrict__ x1l,
    const _Float16* __restrict__ x2h, const _Float16* __restrict__ x2l,
    const float* __restrict__ invn, const float* __restrict__ thr,
    int* __restrict__ row_count)
{
    __shared__ float s_thr[128], s_invn[128];
    __shared__ int cnt_s[128];

    const int tid  = threadIdx.x;
    const int wave = tid >> 6;
    const int lane = tid & 63;
    const int row0 = blockIdx.y * 128;
    const int col0 = blockIdx.x * 128;
    const int wr = (wave >> 1) * 64;   // wave row offset
    const int wc = (wave & 1) * 64;    // wave col offset

    if (tid < 128) {
        cnt_s[tid]  = 0;
        s_thr[tid]  = thr[row0 + tid];
        s_invn[tid] = invn[col0 + tid];
    }

    // per-wave fragment stream bases (lane-contiguous 16B within 1KB blocks)
    const size_t la8 = (size_t)lane * 8;
    const _Float16* pah = x1h + (size_t)((row0 + wr) >> 5) * 4096 + la8;
    const _Float16* pal = x1l + (size_t)((row0 + wr) >> 5) * 4096 + la8;
    const _Float16* pbh = x2h + (size_t)((col0 + wc) >> 5) * 4096 + la8;
    const _Float16* pbl = x2l + (size_t)((col0 + wc) >> 5) * 4096 + la8;

    floatx16 acc[2][2];
    #pragma unroll
    for (int a = 0; a < 2; a++)
        #pragma unroll
        for (int b = 0; b < 2; b++)
            #pragma unroll
            for (int i = 0; i < 16; i++) acc[a][b][i] = 0.f;

    // ---- barrier-free MFMA sweep: 8 K16-steps x {8 coalesced loads + 12 MFMAs} ----
    #pragma unroll
    for (int c = 0; c < 4; c++) {
        #pragma unroll
        for (int k2 = 0; k2 < 2; k2++) {
            const int so = (c * 2 + k2) * 512;
            half8 ah[2], al[2], bh[2], bl[2];
            #pragma unroll
            for (int u = 0; u < 2; u++) {
                ah[u] = *(const half8*)(pah + (size_t)u * 4096 + so);
                al[u] = *(const half8*)(pal + (size_t)u * 4096 + so);
                bh[u] = *(const half8*)(pbh + (size_t)u * 4096 + so);
                bl[u] = *(const half8*)(pbl + (size_t)u * 4096 + so);
            }
            #pragma unroll
            for (int mt = 0; mt < 2; mt++)
                #pragma unroll
                for (int nt = 0; nt < 2; nt++) {
                    acc[mt][nt] = __builtin_amdgcn_mfma_f32_32x32x16_f16(al[mt], bh[nt], acc[mt][nt], 0, 0, 0);
                    acc[mt][nt] = __builtin_amdgcn_mfma_f32_32x32x16_f16(ah[mt], bl[nt], acc[mt][nt], 0, 0, 0);
                    acc[mt][nt] = __builtin_amdgcn_mfma_f32_32x32x16_f16(ah[mt], bh[nt], acc[mt][nt], 0, 0, 0);
                }
        }
    }

    __syncthreads();   // s_thr/s_invn/cnt_s init visible to all waves

    // ---- epilogue: normalize, compare vs diag threshold, ballot-count ----
    // C/D layout (32x32): col = lane&31, row = (reg&3) + 8*(reg>>2) + 4*(lane>>5)
    const int cm = lane & 31;
    const int hw = lane >> 5;
    const float iv0 = s_invn[wc + cm];
    const float iv1 = s_invn[wc + 32 + cm];
    const int gc0 = col0 + wc + cm;
    const int gc1 = gc0 + 32;

    #pragma unroll
    for (int mt = 0; mt < 2; mt++) {
        #pragma unroll
        for (int reg = 0; reg < 16; reg++) {
            const int rbase = wr + mt * 32 + (reg & 3) + 8 * (reg >> 2);
            const int rloc  = rbase + 4 * hw;
            const int grow  = row0 + rloc;
            const float t   = s_thr[rloc];
            const bool p0 = (acc[mt][0][reg] * iv0 > t) && (gc0 != grow);
            const bool p1 = (acc[mt][1][reg] * iv1 > t) && (gc1 != grow);
            const unsigned long long b0 = __ballot(p0);
            const unsigned long long b1 = __ballot(p1);
            if (lane == 0) {
                const int clo = __popcll(b0 & 0xffffffffULL) + __popcll(b1 & 0xffffffffULL);
                if (clo) atomicAdd(&cnt_s[rbase], clo);
            } else if (lane == 32) {
                const int chi = __popcll(b0 >> 32) + __popcll(b1 >> 32);
                if (chi) atomicAdd(&cnt_s[rbase + 4], chi);
            }
        }
    }
    __syncthreads();
    if (tid < 128) {
        const int v = cnt_s[tid];
        if (v) atomicAdd(&row_count[row0 + tid], v);
    }
}

// ---------- Kernel B (fallback, proven): in-kernel conversion path ----------
__global__ __launch_bounds__(256) void count_kernel_conv(
    const float* __restrict__ x1, const float* __restrict__ x2,
    const float* __restrict__ invn, const float* __restrict__ thr,
    int* __restrict__ row_count)
{
    __shared__ __align__(16) _Float16 As_hi[4096], As_lo[4096];
    __shared__ __align__(16) _Float16 Bs_hi[4096], Bs_lo[4096];
    __shared__ float s_thr[128], s_invn[128];
    __shared__ int cnt_s[128];

    const int tid  = threadIdx.x;
    const int wave = tid >> 6;
    const int lane = tid & 63;
    const int row0 = blockIdx.y * 128;
    const int col0 = blockIdx.x * 128;
    const int wr = (wave >> 1) * 64;
    const int wc = (wave & 1) * 64;

    if (tid < 128) {
        cnt_s[tid]  = 0;
        s_thr[tid]  = thr[row0 + tid];
        s_invn[tid] = invn[col0 + tid];
    }

    floatx16 acc[2][2];
    #pragma unroll
    for (int a = 0; a < 2; a++)
        #pragma unroll
        for (int b = 0; b < 2; b++)
            #pragma unroll
            for (int i = 0; i < 16; i++) acc[a][b][i] = 0.f;

    const int sr   = tid >> 1;
    const int sks2 = tid & 1;
    const int wbase = ((sr >> 5) * 2 + sks2) * 512 + (sr & 31) * 8;
    const size_t ga = (size_t)(row0 + sr) * KDIM + sks2 * 16;
    const size_t gb = (size_t)(col0 + sr) * KDIM + sks2 * 16;

    const int wrg = wr >> 5;
    const int wcg = wc >> 5;
    const int lane8 = lane * 8;

    for (int kc = 0; kc < KDIM; kc += 32) {
        __syncthreads();
        {
            const float* p = &x1[ga + kc];
            float v[16];
            *(float4*)&v[0]  = *(const float4*)(p);
            *(float4*)&v[4]  = *(const float4*)(p + 4);
            *(float4*)&v[8]  = *(const float4*)(p + 8);
            *(float4*)&v[12] = *(const float4*)(p + 12);
            half8 h0, h1, l0, l1;
            #pragma unroll
            for (int i = 0; i < 8; i++) {
                _Float16 h = (_Float16)v[i];
                h0[i] = h; l0[i] = (_Float16)(v[i] - (float)h);
                _Float16 g = (_Float16)v[i + 8];
                h1[i] = g; l1[i] = (_Float16)(v[i + 8] - (float)g);
            }
            *(half8*)&As_hi[wbase]       = h0;
            *(half8*)&As_hi[wbase + 256] = h1;
            *(half8*)&As_lo[wbase]       = l0;
            *(half8*)&As_lo[wbase + 256] = l1;
        }
        {
            const float* p = &x2[gb + kc];
            float v[16];
            *(float4*)&v[0]  = *(const float4*)(p);
            *(float4*)&v[4]  = *(const float4*)(p + 4);
            *(float4*)&v[8]  = *(const float4*)(p + 8);
            *(float4*)&v[12] = *(const float4*)(p + 12);
            half8 h0, h1, l0, l1;
            #pragma unroll
            for (int i = 0; i < 8; i++) {
                _Float16 h = (_Float16)v[i];
                h0[i] = h; l0[i] = (_Float16)(v[i] - (float)h);
                _Float16 g = (_Float16)v[i + 8];
                h1[i] = g; l1[i] = (_Float16)(v[i + 8] - (float)g);
            }
            *(half8*)&Bs_hi[wbase]       = h0;
            *(half8*)&Bs_hi[wbase + 256] = h1;
            *(half8*)&Bs_lo[wbase]       = l0;
            *(half8*)&Bs_lo[wbase + 256] = l1;
        }
        __syncthreads();

        #pragma unroll
        for (int ks2 = 0; ks2 < 2; ks2++) {
            half8 ah[2], al[2], bh[2], bl[2];
            #pragma unroll
            for (int t = 0; t < 2; t++) {
                const int oa = ((wrg + t) * 2 + ks2) * 512 + lane8;
                ah[t] = *(const half8*)&As_hi[oa];
                al[t] = *(const half8*)&As_lo[oa];
                const int ob = ((wcg + t) * 2 + ks2) * 512 + lane8;
                bh[t] = *(const half8*)&Bs_hi[ob];
                bl[t] = *(const half8*)&Bs_lo[ob];
            }
            #pragma unroll
            for (int mt = 0; mt < 2; mt++)
                #pragma unroll
                for (int nt = 0; nt < 2; nt++) {
                    acc[mt][nt] = __builtin_amdgcn_mfma_f32_32x32x16_f16(al[mt], bh[nt], acc[mt][nt], 0, 0, 0);
                    acc[mt][nt] = __builtin_amdgcn_mfma_f32_32x32x16_f16(ah[mt], bl[nt], acc[mt][nt], 0, 0, 0);
                    acc[mt][nt] = __builtin_amdgcn_mfma_f32_32x32x16_f16(ah[mt], bh[nt], acc[mt][nt], 0, 0, 0);
                }
        }
    }

    const int cm = lane & 31;
    const int hw = lane >> 5;
    const float iv0 = s_invn[wc + cm];
    const float iv1 = s_invn[wc + 32 + cm];
    const int gc0 = col0 + wc + cm;
    const int gc1 = gc0 + 32;

    #pragma unroll
    for (int mt = 0; mt < 2; mt++) {
        #pragma unroll
        for (int reg = 0; reg < 16; reg++) {
            const int rbase = wr + mt * 32 + (reg & 3) + 8 * (reg >> 2);
            const int rloc  = rbase + 4 * hw;
            const int grow  = row0 + rloc;
            const float t   = s_thr[rloc];
            const bool p0 = (acc[mt][0][reg] * iv0 > t) && (gc0 != grow);
            const bool p1 = (acc[mt][1][reg] * iv1 > t) && (gc1 != grow);
            const unsigned long long b0 = __ballot(p0);
            const unsigned long long b1 = __ballot(p1);
            if (lane == 0) {
                const int clo = __popcll(b0 & 0xffffffffULL) + __popcll(b1 & 0xffffffffULL);
                if (clo) atomicAdd(&cnt_s[rbase], clo);
            } else if (lane == 32) {
                const int chi = __popcll(b0 >> 32) + __popcll(b1 >> 32);
                if (chi) atomicAdd(&cnt_s[rbase + 4], chi);
            }
        }
    }
    __syncthreads();
    if (tid < 128) {
        const int v = cnt_s[tid];
        if (v) atomicAdd(&row_count[row0 + tid], v);
    }
}

// ---------- Kernel C: final reduction ----------
__global__ __launch_bounds__(1024) void finalize_kernel(
    const int* __restrict__ row_count, float* __restrict__ out, int B, int nper)
{
    __shared__ int wsum[16];
    const int t = threadIdx.x;
    int c = 0;
    for (int i = t; i < B; i += 1024) c += (row_count[i] < nper) ? 1 : 0;
    #pragma unroll
    for (int m = 32; m > 0; m >>= 1) c += __shfl_xor(c, m);
    if ((t & 63) == 0) wsum[t >> 6] = c;
    __syncthreads();
    if (t == 0) {
        int tot = 0;
        #pragma unroll
        for (int w = 0; w < 16; w++) tot += wsum[w];
        out[0] = (float)tot / (float)B;
    }
}

extern "C" void kernel_launch(void* const* d_in, const int* in_sizes, int n_in,
                              void* d_out, int out_size, void* d_ws, size_t ws_size,
                              hipStream_t stream)
{
    const float* x1 = (const float*)d_in[0];
    const float* x2 = (const float*)d_in[1];
    const int B = in_sizes[0] / KDIM;     // 8192
    const int S = in_sizes[1] / KDIM;     // 8192
    const int nper = S / 100 + 1;         // 82

    float* invn      = (float*)d_ws;
    float* thr       = invn + S;
    int*   row_count = (int*)(thr + B);

    uintptr_t ap = ((uintptr_t)(row_count + B) + 15) & ~(uintptr_t)15;
    _Float16* x1h = (_Float16*)ap;
    _Float16* x1l = x1h + (size_t)B * KDIM;
    _Float16* x2h = x1l + (size_t)B * KDIM;
    _Float16* x2l = x2h + (size_t)S * KDIM;
    const size_t need = (size_t)((char*)(x2l + (size_t)S * KDIM) - (char*)d_ws);
    // fast path: ws for planes + 128-divisible dims (fragment-major superblocks)
    const int fast = (ws_size >= need && (B % 128) == 0 && (S % 128) == 0) ? 1 : 0;

    const int mx = (B > S) ? B : S;
    prep_kernel<<<(mx + 31) / 32, 256, 0, stream>>>(
        x1, x2, invn, thr, row_count,
        (unsigned*)x1h, (unsigned*)x1l, (unsigned*)x2h, (unsigned*)x2l,
        B, S, fast);

    dim3 grid(S / 128, B / 128);
    if (fast)
        count_kernel_fast<<<grid, 256, 0, stream>>>(
            x1h, x1l, x2h, x2l, invn, thr, row_count);
    else
        count_kernel_conv<<<grid, 256, 0, stream>>>(x1, x2, invn, thr, row_count);

    finalize_kernel<<<1, 1024, 0, stream>>>(row_count, (float*)d_out, B, nper);
}

// Round 10
// 124.204 us; speedup vs baseline: 11.9443x; 1.0095x over previous
//
#include <hip/hip_runtime.h>

// out = mean_i( rank_of_diag(cos_sim(x1,x2))_i < nper ), nper = S/100+1.
// rank_i = #{ j != i : dot(x1_i,x2_j)*inv||x2_j|| > dot(x1_i,x2_i)*inv||x2_i|| }
// GEMM via fp16x3 (Markidis split) MFMA: x=hi+lo; hi*hi + hi*lo + lo*hi.
// Dropped lo*lo ~2^-22 rel/term -> dot err ~3e-6 << 4.5e-3 order-stat spacing.
//
// R10: R9 + FORCED 1-step register prefetch in count. R9 analysis: VGPR=64
// proves zero compiler lookahead; each K16-step pays ~400cyc L2 latency
// serially before 384cyc of MFMA (convoy, MfmaUtil 31%). R5's prefetch was
// silently sunk by the scheduler; this time LOADSET(s+1) is pinned before
// step s's MFMAs with __builtin_amdgcn_sched_barrier(0) -> compiler emits a
// counted vmcnt wait (step-s loads drained, s+1 in flight). Named fA/fB sets
// (static indexing, no scratch). Expect VGPR ~96-112; if it stays ~64 the
// compiler defeated it again.
// R8 lesson: no __threadfence in wide grids (L2 writeback+inv poisons L2).
// R7 lesson: launch_bounds(256,8) caps regs at 64 -> acc spills to scratch.
//
// Fragment-major plane layout (per plane, halves):
//   addr(row,k) = (row>>5)*4096 + ((k>>5)*2 + ((k>>4)&1))*512
//               + ((k>>3)&1)*256 + (row&31)*8 + (k&7)
// -> 32-row x 16-half fragment = contiguous 1KB, lane reads 16B at +lane*8.

#define KDIM 128

typedef _Float16 half8 __attribute__((ext_vector_type(8)));
typedef float floatx16 __attribute__((ext_vector_type(16)));

// ---------- Kernel A: norms/threshold + coalesced fragment-major fp16 planes ----------
__global__ __launch_bounds__(256) void prep_kernel(
    const float* __restrict__ x1, const float* __restrict__ x2,
    float* __restrict__ invn, float* __restrict__ thr,
    int* __restrict__ row_count,
    unsigned* __restrict__ x1h, unsigned* __restrict__ x1l,
    unsigned* __restrict__ x2h, unsigned* __restrict__ x2l,
    int B, int S, int wplanes)
{
    __shared__ __align__(16) unsigned s1h[2048], s1l[2048], s2h[2048], s2l[2048];
    const int tid  = threadIdx.x;
    const int row0 = blockIdx.x * 32;
    const int fr   = tid >> 3;          // row within superblock (0..31)
    const int kg   = tid & 7;           // k16-group (0..7)
    const int r    = row0 + fr;

    const bool inB = (r < B);
    const bool inS = (r < S);

    float a[16], b[16];
    float s22 = 0.f, s12 = 0.f;
    if (inB) {
        const float4* p = (const float4*)&x1[(size_t)r * KDIM + kg * 16];
        *(float4*)&a[0]  = p[0];
        *(float4*)&a[4]  = p[1];
        *(float4*)&a[8]  = p[2];
        *(float4*)&a[12] = p[3];
    } else {
        #pragma unroll
        for (int i = 0; i < 16; i++) a[i] = 0.f;
    }
    if (inS) {
        const float4* p = (const float4*)&x2[(size_t)r * KDIM + kg * 16];
        *(float4*)&b[0]  = p[0];
        *(float4*)&b[4]  = p[1];
        *(float4*)&b[8]  = p[2];
        *(float4*)&b[12] = p[3];
        #pragma unroll
        for (int i = 0; i < 16; i++) {
            s22 = fmaf(b[i], b[i], s22);
            s12 = fmaf(a[i], b[i], s12);
        }
    } else {
        #pragma unroll
        for (int i = 0; i < 16; i++) b[i] = 0.f;
    }
    // reduce across the 8 threads of this row (contiguous lanes)
    #pragma unroll
    for (int m = 1; m <= 4; m <<= 1) {
        s22 += __shfl_xor(s22, m);
        s12 += __shfl_xor(s12, m);
    }
    if (kg == 0 && inS) {
        const float iv = rsqrtf(s22);
        invn[r] = iv;
        if (inB) thr[r] = s12 * iv;
    }
    if (kg == 1 && inB) row_count[r] = 0;

    if (wplanes) {
        // fragment-major LDS stash
        const int i0 = kg * 256 + fr * 4;
        #pragma unroll
        for (int i = 0; i < 4; i++) {
            union { _Float16 h[2]; unsigned u; } hh, ll;
            hh.h[0] = (_Float16)a[2*i];     ll.h[0] = (_Float16)(a[2*i]     - (float)hh.h[0]);
            hh.h[1] = (_Float16)a[2*i+1];   ll.h[1] = (_Float16)(a[2*i+1]   - (float)hh.h[1]);
            s1h[i0 + i] = hh.u;  s1l[i0 + i] = ll.u;
        }
        #pragma unroll
        for (int i = 4; i < 8; i++) {
            union { _Float16 h[2]; unsigned u; } hh, ll;
            hh.h[0] = (_Float16)a[2*i];     ll.h[0] = (_Float16)(a[2*i]     - (float)hh.h[0]);
            hh.h[1] = (_Float16)a[2*i+1];   ll.h[1] = (_Float16)(a[2*i+1]   - (float)hh.h[1]);
            s1h[i0 + 128 + i - 4] = hh.u;  s1l[i0 + 128 + i - 4] = ll.u;
        }
        #pragma unroll
        for (int i = 0; i < 4; i++) {
            union { _Float16 h[2]; unsigned u; } hh, ll;
            hh.h[0] = (_Float16)b[2*i];     ll.h[0] = (_Float16)(b[2*i]     - (float)hh.h[0]);
            hh.h[1] = (_Float16)b[2*i+1];   ll.h[1] = (_Float16)(b[2*i+1]   - (float)hh.h[1]);
            s2h[i0 + i] = hh.u;  s2l[i0 + i] = ll.u;
        }
        #pragma unroll
        for (int i = 4; i < 8; i++) {
            union { _Float16 h[2]; unsigned u; } hh, ll;
            hh.h[0] = (_Float16)b[2*i];     ll.h[0] = (_Float16)(b[2*i]     - (float)hh.h[0]);
            hh.h[1] = (_Float16)b[2*i+1];   ll.h[1] = (_Float16)(b[2*i+1]   - (float)hh.h[1]);
            s2h[i0 + 128 + i - 4] = hh.u;  s2l[i0 + 128 + i - 4] = ll.u;
        }
        __syncthreads();
        // coalesced writeout: thread tid covers u32s [tid*8, tid*8+8)
        const size_t gb = (size_t)(row0 >> 5) * 2048 + (size_t)tid * 8;
        const int lb = tid * 8;
        if (row0 < B) {
            *(uint4*)&x1h[gb]     = *(const uint4*)&s1h[lb];
            *(uint4*)&x1h[gb + 4] = *(const uint4*)&s1h[lb + 4];
            *(uint4*)&x1l[gb]     = *(const uint4*)&s1l[lb];
            *(uint4*)&x1l[gb + 4] = *(const uint4*)&s1l[lb + 4];
        }
        if (row0 < S) {
            *(uint4*)&x2h[gb]     = *(const uint4*)&s2h[lb];
            *(uint4*)&x2h[gb + 4] = *(const uint4*)&s2h[lb + 4];
            *(uint4*)&x2l[gb]     = *(const uint4*)&s2l[lb];
            *(uint4*)&x2l[gb + 4] = *(const uint4*)&s2l[lb + 4];
        }
    }
}

// ---------- Kernel B (fast): zero-LDS zero-barrier streamed fp16x3 GEMM + count ----------
// R4 structure + forced double-buffered register prefetch (fA/fB), pinned
// with sched_barrier(0) so loads for step s+1 are issued before step s MFMAs.
__global__ __launch_bounds__(256, 3) void count_kernel_fast(
    const _Float16* __restrict__ x1h, const _Float16* __restrict__ x1l,
    const _Float16* __restrict__ x2h, const _Float16* __restrict__ x2l,
    const float* __restrict__ invn, const float* __restrict__ thr,
    int* __restrict__ row_count)
{
    __shared__ float s_thr[128], s_invn[128];
    __shared__ int cnt_s[128];

    const int tid  = threadIdx.x;
    const int wave = tid >> 6;
    const int lane = tid & 63;
    const int row0 = blockIdx.y * 128;
    const int col0 = blockIdx.x * 128;
    const int wr = (wave >> 1) * 64;   // wave row offset
    const int wc = (wave & 1) * 64;    // wave col offset

    if (tid < 128) {
        cnt_s[tid]  = 0;
        s_thr[tid]  = thr[row0 + tid];
        s_invn[tid] = invn[col0 + tid];
    }

    // per-wave fragment stream bases (lane-contiguous 16B within 1KB blocks)
    const size_t la8 = (size_t)lane * 8;
    const _Float16* pah = x1h + (size_t)((row0 + wr) >> 5) * 4096 + la8;
    const _Float16* pal = x1l + (size_t)((row0 + wr) >> 5) * 4096 + la8;
    const _Float16* pbh = x2h + (size_t)((col0 + wc) >> 5) * 4096 + la8;
    const _Float16* pbl = x2l + (size_t)((col0 + wc) >> 5) * 4096 + la8;

    floatx16 acc[2][2];
    #pragma unroll
    for (int a = 0; a < 2; a++)
        #pragma unroll
        for (int b = 0; b < 2; b++)
            #pragma unroll
            for (int i = 0; i < 16; i++) acc[a][b][i] = 0.f;

    // F[0]=ah0 F[1]=ah1 F[2]=al0 F[3]=al1 F[4]=bh0 F[5]=bh1 F[6]=bl0 F[7]=bl1
#define LOADSET(F, so)                                            \
    do {                                                          \
        F[0] = *(const half8*)(pah + (so));                       \
        F[1] = *(const half8*)(pah + 4096 + (so));                \
        F[2] = *(const half8*)(pal + (so));                       \
        F[3] = *(const half8*)(pal + 4096 + (so));                \
        F[4] = *(const half8*)(pbh + (so));                       \
        F[5] = *(const half8*)(pbh + 4096 + (so));                \
        F[6] = *(const half8*)(pbl + (so));                       \
        F[7] = *(const half8*)(pbl + 4096 + (so));                \
    } while (0)

    // same accumulation order as R4/R9 (bitwise-identical result)
#define MFMAS(F)                                                                           \
    do {                                                                                   \
        acc[0][0] = __builtin_amdgcn_mfma_f32_32x32x16_f16(F[2], F[4], acc[0][0], 0, 0, 0);\
        acc[0][0] = __builtin_amdgcn_mfma_f32_32x32x16_f16(F[0], F[6], acc[0][0], 0, 0, 0);\
        acc[0][0] = __builtin_amdgcn_mfma_f32_32x32x16_f16(F[0], F[4], acc[0][0], 0, 0, 0);\
        acc[0][1] = __builtin_amdgcn_mfma_f32_32x32x16_f16(F[2], F[5], acc[0][1], 0, 0, 0);\
        acc[0][1] = __builtin_amdgcn_mfma_f32_32x32x16_f16(F[0], F[7], acc[0][1], 0, 0, 0);\
        acc[0][1] = __builtin_amdgcn_mfma_f32_32x32x16_f16(F[0], F[5], acc[0][1], 0, 0, 0);\
        acc[1][0] = __builtin_amdgcn_mfma_f32_32x32x16_f16(F[3], F[4], acc[1][0], 0, 0, 0);\
        acc[1][0] = __builtin_amdgcn_mfma_f32_32x32x16_f16(F[1], F[6], acc[1][0], 0, 0, 0);\
        acc[1][0] = __builtin_amdgcn_mfma_f32_32x32x16_f16(F[1], F[4], acc[1][0], 0, 0, 0);\
        acc[1][1] = __builtin_amdgcn_mfma_f32_32x32x16_f16(F[3], F[5], acc[1][1], 0, 0, 0);\
        acc[1][1] = __builtin_amdgcn_mfma_f32_32x32x16_f16(F[1], F[7], acc[1][1], 0, 0, 0);\
        acc[1][1] = __builtin_amdgcn_mfma_f32_32x32x16_f16(F[1], F[5], acc[1][1], 0, 0, 0);\
    } while (0)

    half8 fA[8], fB[8];
    LOADSET(fA, 0);
    #pragma unroll
    for (int s = 0; s < 8; s++) {
        if ((s & 1) == 0) {
            if (s < 7) LOADSET(fB, (s + 1) * 512);
            __builtin_amdgcn_sched_barrier(0);   // pin prefetch before MFMAs
            MFMAS(fA);
        } else {
            if (s < 7) LOADSET(fA, (s + 1) * 512);
            __builtin_amdgcn_sched_barrier(0);
            MFMAS(fB);
        }
    }
#undef LOADSET
#undef MFMAS

    __syncthreads();   // s_thr/s_invn/cnt_s init visible to all waves

    // ---- epilogue: normalize, compare vs diag threshold, ballot-count ----
    // C/D layout (32x32): col = lane&31, row = (reg&3) + 8*(reg>>2) + 4*(lane>>5)
    const int cm = lane & 31;
    const int hw = lane >> 5;
    const float iv0 = s_invn[wc + cm];
    const float iv1 = s_invn[wc + 32 + cm];
    const int gc0 = col0 + wc + cm;
    const int gc1 = gc0 + 32;

    #pragma unroll
    for (int mt = 0; mt < 2; mt++) {
        #pragma unroll
        for (int reg = 0; reg < 16; reg++) {
            const int rbase = wr + mt * 32 + (reg & 3) + 8 * (reg >> 2);
            const int rloc  = rbase + 4 * hw;
            const int grow  = row0 + rloc;
            const float t   = s_thr[rloc];
            const bool p0 = (acc[mt][0][reg] * iv0 > t) && (gc0 != grow);
            const bool p1 = (acc[mt][1][reg] * iv1 > t) && (gc1 != grow);
            const unsigned long long b0 = __ballot(p0);
            const unsigned long long b1 = __ballot(p1);
            if (lane == 0) {
                const int clo = __popcll(b0 & 0xffffffffULL) + __popcll(b1 & 0xffffffffULL);
                if (clo) atomicAdd(&cnt_s[rbase], clo);
            } else if (lane == 32) {
                const int chi = __popcll(b0 >> 32) + __popcll(b1 >> 32);
                if (chi) atomicAdd(&cnt_s[rbase + 4], chi);
            }
        }
    }
    __syncthreads();
    if (tid < 128) {
        const int v = cnt_s[tid];
        if (v) atomicAdd(&row_count[row0 + tid], v);
    }
}

// ---------- Kernel B (fallback, proven): in-kernel conversion path ----------
__global__ __launch_bounds__(256) void count_kernel_conv(
    const float* __restrict__ x1, const float* __restrict__ x2,
    const float* __restrict__ invn, const float* __restrict__ thr,
    int* __restrict__ row_count)
{
    __shared__ __align__(16) _Float16 As_hi[4096], As_lo[4096];
    __shared__ __align__(16) _Float16 Bs_hi[4096], Bs_lo[4096];
    __shared__ float s_thr[128], s_invn[128];
    __shared__ int cnt_s[128];

    const int tid  = threadIdx.x;
    const int wave = tid >> 6;
    const int lane = tid & 63;
    const int row0 = blockIdx.y * 128;
    const int col0 = blockIdx.x * 128;
    const int wr = (wave >> 1) * 64;
    const int wc = (wave & 1) * 64;

    if (tid < 128) {
        cnt_s[tid]  = 0;
        s_thr[tid]  = thr[row0 + tid];
        s_invn[tid] = invn[col0 + tid];
    }

    floatx16 acc[2][2];
    #pragma unroll
    for (int a = 0; a < 2; a++)
        #pragma unroll
        for (int b = 0; b < 2; b++)
            #pragma unroll
            for (int i = 0; i < 16; i++) acc[a][b][i] = 0.f;

    const int sr   = tid >> 1;
    const int sks2 = tid & 1;
    const int wbase = ((sr >> 5) * 2 + sks2) * 512 + (sr & 31) * 8;
    const size_t ga = (size_t)(row0 + sr) * KDIM + sks2 * 16;
    const size_t gb = (size_t)(col0 + sr) * KDIM + sks2 * 16;

    const int wrg = wr >> 5;
    const int wcg = wc >> 5;
    const int lane8 = lane * 8;

    for (int kc = 0; kc < KDIM; kc += 32) {
        __syncthreads();
        {
            const float* p = &x1[ga + kc];
            float v[16];
            *(float4*)&v[0]  = *(const float4*)(p);
            *(float4*)&v[4]  = *(const float4*)(p + 4);
            *(float4*)&v[8]  = *(const float4*)(p + 8);
            *(float4*)&v[12] = *(const float4*)(p + 12);
            half8 h0, h1, l0, l1;
            #pragma unroll
            for (int i = 0; i < 8; i++) {
                _Float16 h = (_Float16)v[i];
                h0[i] = h; l0[i] = (_Float16)(v[i] - (float)h);
                _Float16 g = (_Float16)v[i + 8];
                h1[i] = g; l1[i] = (_Float16)(v[i + 8] - (float)g);
            }
            *(half8*)&As_hi[wbase]       = h0;
            *(half8*)&As_hi[wbase + 256] = h1;
            *(half8*)&As_lo[wbase]       = l0;
            *(half8*)&As_lo[wbase + 256] = l1;
        }
        {
            const float* p = &x2[gb + kc];
            float v[16];
            *(float4*)&v[0]  = *(const float4*)(p);
            *(float4*)&v[4]  = *(const float4*)(p + 4);
            *(float4*)&v[8]  = *(const float4*)(p + 8);
            *(float4*)&v[12] = *(const float4*)(p + 12);
            half8 h0, h1, l0, l1;
            #pragma unroll
            for (int i = 0; i < 8; i++) {
                _Float16 h = (_Float16)v[i];
                h0[i] = h; l0[i] = (_Float16)(v[i] - (float)h);
                _Float16 g = (_Float16)v[i + 8];
                h1[i] = g; l1[i] = (_Float16)(v[i + 8] - (float)g);
            }
            *(half8*)&Bs_hi[wbase]       = h0;
            *(half8*)&Bs_hi[wbase + 256] = h1;
            *(half8*)&Bs_lo[wbase]       = l0;
            *(half8*)&Bs_lo[wbase + 256] = l1;
        }
        __syncthreads();

        #pragma unroll
        for (int ks2 = 0; ks2 < 2; ks2++) {
            half8 ah[2], al[2], bh[2], bl[2];
            #pragma unroll
            for (int t = 0; t < 2; t++) {
                const int oa = ((wrg + t) * 2 + ks2) * 512 + lane8;
                ah[t] = *(const half8*)&As_hi[oa];
                al[t] = *(const half8*)&As_lo[oa];
                const int ob = ((wcg + t) * 2 + ks2) * 512 + lane8;
                bh[t] = *(const half8*)&Bs_hi[ob];
                bl[t] = *(const half8*)&Bs_lo[ob];
            }
            #pragma unroll
            for (int mt = 0; mt < 2; mt++)
                #pragma unroll
                for (int nt = 0; nt < 2; nt++) {
                    acc[mt][nt] = __builtin_amdgcn_mfma_f32_32x32x16_f16(al[mt], bh[nt], acc[mt][nt], 0, 0, 0);
                    acc[mt][nt] = __builtin_amdgcn_mfma_f32_32x32x16_f16(ah[mt], bl[nt], acc[mt][nt], 0, 0, 0);
                    acc[mt][nt] = __builtin_amdgcn_mfma_f32_32x32x16_f16(ah[mt], bh[nt], acc[mt][nt], 0, 0, 0);
                }
        }
    }

    const int cm = lane & 31;
    const int hw = lane >> 5;
    const float iv0 = s_invn[wc + cm];
    const float iv1 = s_invn[wc + 32 + cm];
    const int gc0 = col0 + wc + cm;
    const int gc1 = gc0 + 32;

    #pragma unroll
    for (int mt = 0; mt < 2; mt++) {
        #pragma unroll
        for (int reg = 0; reg < 16; reg++) {
            const int rbase = wr + mt * 32 + (reg & 3) + 8 * (reg >> 2);
            const int rloc  = rbase + 4 * hw;
            const int grow  = row0 + rloc;
            const float t   = s_thr[rloc];
            const bool p0 = (acc[mt][0][reg] * iv0 > t) && (gc0 != grow);
            const bool p1 = (acc[mt][1][reg] * iv1 > t) && (gc1 != grow);
            const unsigned long long b0 = __ballot(p0);
            const unsigned long long b1 = __ballot(p1);
            if (lane == 0) {
                const int clo = __popcll(b0 & 0xffffffffULL) + __popcll(b1 & 0xffffffffULL);
                if (clo) atomicAdd(&cnt_s[rbase], clo);
            } else if (lane == 32) {
                const int chi = __popcll(b0 >> 32) + __popcll(b1 >> 32);
                if (chi) atomicAdd(&cnt_s[rbase + 4], chi);
            }
        }
    }
    __syncthreads();
    if (tid < 128) {
        const int v = cnt_s[tid];
        if (v) atomicAdd(&row_count[row0 + tid], v);
    }
}

// ---------- Kernel C: final reduction ----------
__global__ __launch_bounds__(1024) void finalize_kernel(
    const int* __restrict__ row_count, float* __restrict__ out, int B, int nper)
{
    __shared__ int wsum[16];
    const int t = threadIdx.x;
    int c = 0;
    for (int i = t; i < B; i += 1024) c += (row_count[i] < nper) ? 1 : 0;
    #pragma unroll
    for (int m = 32; m > 0; m >>= 1) c += __shfl_xor(c, m);
    if ((t & 63) == 0) wsum[t >> 6] = c;
    __syncthreads();
    if (t == 0) {
        int tot = 0;
        #pragma unroll
        for (int w = 0; w < 16; w++) tot += wsum[w];
        out[0] = (float)tot / (float)B;
    }
}

extern "C" void kernel_launch(void* const* d_in, const int* in_sizes, int n_in,
                              void* d_out, int out_size, void* d_ws, size_t ws_size,
                              hipStream_t stream)
{
    const float* x1 = (const float*)d_in[0];
    const float* x2 = (const float*)d_in[1];
    const int B = in_sizes[0] / KDIM;     // 8192
    const int S = in_sizes[1] / KDIM;     // 8192
    const int nper = S / 100 + 1;         // 82

    float* invn      = (float*)d_ws;
    float* thr       = invn + S;
    int*   row_count = (int*)(thr + B);

    uintptr_t ap = ((uintptr_t)(row_count + B) + 15) & ~(uintptr_t)15;
    _Float16* x1h = (_Float16*)ap;
    _Float16* x1l = x1h + (size_t)B * KDIM;
    _Float16* x2h = x1l + (size_t)B * KDIM;
    _Float16* x2l = x2h + (size_t)S * KDIM;
    const size_t need = (size_t)((char*)(x2l + (size_t)S * KDIM) - (char*)d_ws);
    // fast path: ws for planes + 128-divisible dims (fragment-major superblocks)
    const int fast = (ws_size >= need && (B % 128) == 0 && (S % 128) == 0) ? 1 : 0;

    const int mx = (B > S) ? B : S;
    prep_kernel<<<(mx + 31) / 32, 256, 0, stream>>>(
        x1, x2, invn, thr, row_count,
        (unsigned*)x1h, (unsigned*)x1l, (unsigned*)x2h, (unsigned*)x2l,
        B, S, fast);

    dim3 grid(S / 128, B / 128);
    if (fast)
        count_kernel_fast<<<grid, 256, 0, stream>>>(
            x1h, x1l, x2h, x2l, invn, thr, row_count);
    else
        count_kernel_conv<<<grid, 256, 0, stream>>>(x1, x2, invn, thr, row_count);

    finalize_kernel<<<1, 1024, 0, stream>>>(row_count, (float*)d_out, B, nper);
}